// Round 2
// baseline (349.208 us; speedup 1.0000x reference)
//
#include <hip/hip_runtime.h>
#include <math.h>

#define BB 32
#define NCLS 15
#define HH 256
#define WW 256
#define KK 500
#define HW (HH*WW)                 // 65536
#define NELEM (BB*NCLS*HW)         // 31457280
#define N4 (NELEM/4)               // 7864320 float4s
#define NSLOT (NCLS*16*16)         // 3840 per-batch multiplier slots (fits LDS)

// Single fused kernel:
//   blocks 0..31        : per-batch aux work (huber/l_bk/last, scatter-multiply
//                         dedup in LDS, correction terms) — scheduled first so
//                         their ~3 us hides under the streaming blocks.
//   blocks 32..1951     : streaming sweep, one quarter of one (b,c) slab each
//                         (gamma block-uniform in SGPR, nt dwordx4 MLP-8).
// All cross-block state in __device__ globals; the last block (monotone
// counter % grid) finalizes out[0] and self-resets the globals for the next
// iteration / rocprof replay. d_ws is UNUSED (harness poison is harmless).
#define AUXB 32
#define FG (AUXB + 1920)
#define FT 256
#define SLAB4 16384                // float4s per (b,c) slab
#define QUART 4096                 // float4s per streaming block

typedef float v4f __attribute__((ext_vector_type(4)));

__constant__ float c_gammas[15] = {2.7f,2.1f,2.4f,2.0f,3.0f,2.9f,3.0f,2.5f,
                                   2.1f,2.6f,2.0f,2.1f,2.7f,2.4f,2.2f};

// Raw HW transcendentals (glibc collides with __exp2f/__log2f names):
#define EXP2F(x) __builtin_amdgcn_exp2f(x)
#define LOG2F(x) __builtin_amdgcn_logf(x)
#define LN2 0.69314718055994530942f

// Self-resetting cross-block accumulators (load-initialized; finalizer
// restores these exact values every iteration, so graph replay is safe).
__device__ float g_S = 0.0f;
__device__ float g_np = 0.0f;
__device__ unsigned long long g_lastpack = 0ULL;   // ((t+1)<<32) | bits(l_bk)
__device__ unsigned int g_count = 0u;              // monotone; used mod FG

__device__ __forceinline__ float elem(float p, float g, float gam, float& np) {
    float t    = 1.0f - g;
    float t2   = t * t;
    float negw = (g < 1.0f) ? t2 * t2 : 0.0f;          // (1-g)^4 * neg_ind
    float pw   = EXP2F(gam * LOG2F(p));                // p^gam (0 -> 0)
    float v    = (LN2 * LOG2F(1.0f - p + 1e-12f)) * pw * negw;
    if (g == 1.0f) {                                   // ~never taken
        np += 1.0f;
        v += (LN2 * LOG2F(p + 1e-12f)) * EXP2F(gam * LOG2F(1.0f - p));
    }
    return v;
}

// Sum of 4 elems, UNSCALED by gamma (gamma block-uniform, factored out).
__device__ __forceinline__ float elem4(v4f p, v4f g, float gam, float& np) {
    return elem(p.x, g.x, gam, np) + elem(p.y, g.y, gam, np)
         + elem(p.z, g.z, gam, np) + elem(p.w, g.w, gam, np);
}

__device__ __forceinline__ float blockReduceSum(float v) {
    __shared__ float sh[4];
    #pragma unroll
    for (int o = 32; o > 0; o >>= 1) v += __shfl_down(v, o);
    int lane = threadIdx.x & 63, w = threadIdx.x >> 6;
    if (lane == 0) sh[w] = v;
    __syncthreads();
    float r = 0.0f;
    if (threadIdx.x == 0) r = sh[0] + sh[1] + sh[2] + sh[3];
    __syncthreads();
    return r;   // valid on thread 0 only
}

__global__ __launch_bounds__(256) void k_mega(const v4f*   __restrict__ pred4,
                                              const v4f*   __restrict__ gt4,
                                              const float* __restrict__ pred,
                                              const float* __restrict__ gt,
                                              const float* __restrict__ output,
                                              const int*   __restrict__ mask,
                                              const int*   __restrict__ ind,
                                              const float* __restrict__ target,
                                              const int*   __restrict__ inde,
                                              float* out) {
    __shared__ float shM[NSLOT];             // per-batch multiplier table
    __shared__ unsigned long long shL[4];    // lastpack wave partials
    const int tid = threadIdx.x;
    const int blk = blockIdx.x;

    float acc = 0.0f;          // gamma-scaled contributions (corr terms)
    float np  = 0.0f;

    if (blk < AUXB) {
        // ---------- aux block: batch b = blk ----------
        const int b = blk;
        for (int i = tid; i < NSLOT; i += FT) shM[i] = 1.0f;
        __syncthreads();

        unsigned long long lp = 0ULL;
        for (int k = tid; k < KK; k += FT) {
            int t = b * KK + k;
            int pos = ind[t];                                // 0..HW-1
            const float* ob = output + (size_t)b * 2 * HW;
            float p0 = ob[pos];
            float p1 = ob[HW + pos];
            float d0 = p0 - target[t*2 + 0];
            float d1 = p1 - target[t*2 + 1];
            float a0 = fabsf(d0), a1 = fabsf(d1);
            float h0 = (a0 < 1.0f) ? 0.5f*d0*d0 : a0 - 0.5f;
            float h1 = (a1 < 1.0f) ? 0.5f*d1*d1 : a1 - 0.5f;
            float l  = 0.5f * (h0 + h1);
            if (mask[t] != 0) {
                unsigned long long pk =
                    ((unsigned long long)(unsigned)(t + 1) << 32) |
                    (unsigned long long)__float_as_uint(l);
                lp = (pk > lp) ? pk : lp;
                float factor = atanf(l) * 0.63661977236758134308f;  // 2/pi
                int ch = inde[t*3 + 0];
                int yy = inde[t*3 + 1];
                int xx = inde[t*3 + 2];
                int mi = (ch*16 + yy)*16 + xx;
                unsigned int* addr = (unsigned int*)&shM[mi];
                unsigned int old = *addr, assumed;
                do {
                    assumed = old;
                    float nv = __uint_as_float(assumed) * factor;
                    old = atomicCAS(addr, assumed, __float_as_uint(nv));
                } while (old != assumed);
            }
        }
        // block-max of lastpack -> one global atomicMax per aux block
        #pragma unroll
        for (int o = 32; o > 0; o >>= 1) {
            unsigned long long other = __shfl_down(lp, o);
            lp = (other > lp) ? other : lp;
        }
        int lane = tid & 63, w = tid >> 6;
        if (lane == 0) shL[w] = lp;
        __syncthreads();
        if (tid == 0) {
            unsigned long long m0 = shL[0] > shL[1] ? shL[0] : shL[1];
            unsigned long long m1 = shL[2] > shL[3] ? shL[2] : shL[3];
            unsigned long long mm = m0 > m1 ? m0 : m1;
            if (mm) atomicMax(&g_lastpack, mm);
        }
        __syncthreads();                     // scatters complete before scan

        // correction at scatter-modified slots (dedup'd by construction)
        for (int i = tid; i < NSLOT; i += FT) {
            float m = shM[i];
            if (m != 1.0f) {
                int ch = i >> 8;
                int yy = (i >> 4) & 15;
                int xx = i & 15;
                size_t off = ((size_t)(b*NCLS + ch) << 16) + (yy*WW + xx);
                float p = pred[off];
                float g = gt[off];
                float gam = c_gammas[ch];
                float dmy = 0.0f;            // num_pos unaffected by corr
                acc += gam * (elem(p*m, g, gam, dmy) - elem(p, g, gam, dmy));
            }
        }
    } else {
        // ---------- streaming block ----------
        const int sblk = blk - AUXB;
        const int slab = sblk >> 2;              // (b*15 + c)
        const int c    = slab % NCLS;            // SGPR-uniform
        const float gam = c_gammas[c];           // one scalar load per block
        const int base = slab * SLAB4 + (sblk & 3) * QUART + tid;

        float sacc = 0.0f;
        #pragma unroll 1
        for (int k = 0; k < 4; ++k) {
            int i0 = base + k * 1024;
            // 8 independent nt loads; pred/gt interleaved so quad0 waits at
            // vmcnt(6), keeping 6 loads in flight under its compute
            v4f p0 = __builtin_nontemporal_load(pred4 + i0);
            v4f g0 = __builtin_nontemporal_load(gt4   + i0);
            v4f p1 = __builtin_nontemporal_load(pred4 + i0 + 256);
            v4f g1 = __builtin_nontemporal_load(gt4   + i0 + 256);
            v4f p2 = __builtin_nontemporal_load(pred4 + i0 + 512);
            v4f g2 = __builtin_nontemporal_load(gt4   + i0 + 512);
            v4f p3 = __builtin_nontemporal_load(pred4 + i0 + 768);
            v4f g3 = __builtin_nontemporal_load(gt4   + i0 + 768);
            sacc += elem4(p0, g0, gam, np);
            sacc += elem4(p1, g1, gam, np);
            sacc += elem4(p2, g2, gam, np);
            sacc += elem4(p3, g3, gam, np);
        }
        acc = gam * sacc;                        // gamma factored out
    }

    // ---------- global accumulate + last-block finalize ----------
    float bs = blockReduceSum(acc);
    float bn = blockReduceSum(np);
    if (tid == 0) {
        if (bs != 0.0f) atomicAdd(&g_S, bs);
        if (bn != 0.0f) atomicAdd(&g_np, bn);
        __threadfence();                         // adds visible before count
        unsigned int done = atomicAdd(&g_count, 1u);
        if (done % FG == FG - 1) {               // last block this iteration
            float S   = atomicAdd(&g_S, 0.0f);   // coherent reads
            float npv = atomicAdd(&g_np, 0.0f);
            unsigned long long lpv = atomicAdd(&g_lastpack, 0ULL);
            float loss0 = (lpv >> 32) ?
                __uint_as_float((unsigned int)(lpv & 0xffffffffu)) : 0.0f;
            float loss = loss0 - 0.5f * S;
            out[0] = (npv == 0.0f) ? loss : loss / npv;
            // self-reset for the next iteration / replay
            atomicExch(&g_S, 0.0f);
            atomicExch(&g_np, 0.0f);
            atomicExch(&g_lastpack, 0ULL);
        }
    }
}

extern "C" void kernel_launch(void* const* d_in, const int* in_sizes, int n_in,
                              void* d_out, int out_size, void* d_ws, size_t ws_size,
                              hipStream_t stream) {
    const float* pred   = (const float*)d_in[0];
    const float* gt     = (const float*)d_in[1];
    const float* output = (const float*)d_in[2];
    const int*   mask   = (const int*)d_in[3];
    const int*   ind    = (const int*)d_in[4];
    const float* target = (const float*)d_in[5];
    const int*   inde   = (const int*)d_in[6];
    float* out = (float*)d_out;
    (void)d_ws; (void)ws_size;                   // workspace unused

    k_mega<<<FG, FT, 0, stream>>>((const v4f*)pred, (const v4f*)gt,
                                  pred, gt, output, mask, ind, target, inde,
                                  out);
}

// Round 3
// 325.022 us; speedup vs baseline: 1.0744x; 1.0744x over previous
//
#include <hip/hip_runtime.h>
#include <math.h>

#define BB 32
#define NCLS 15
#define HH 256
#define WW 256
#define KK 500
#define HW (HH*WW)                 // 65536
#define NELEM (BB*NCLS*HW)         // 31457280
#define N4 (NELEM/4)               // 7864320 float4s
#define NM (BB*NCLS*16*16)         // 122880 multiplier slots
#define BK (BB*KK)                 // 16000

// R3: revert to the proven R1 3-kernel structure (R2's all-in-one LDS mega
// kernel collapsed VGPR to 24 -> ~1 load in flight -> 1.77 TB/s, +55 us).
// Streaming is now an EXPLICIT double-buffered pipeline: two named register
// sets, prefetch batch k+1 issued before computing batch k, pinned with
// sched_barrier(0). Forces vmcnt(8)-style overlap (8 loads always in
// flight) instead of the compiler's pressure-minimizing serialization.
// 960 blocks (half (b,c) slab each, 8 batches of 1024 float4) -> all
// co-resident at 4 blocks/CU under __launch_bounds__(256,4).
#define FG 960
#define FT 256
#define SLAB4 16384                // float4s per (b,c) slab
#define HALF4 8192                 // float4s per block
#define BKPB 17                    // bk items per block (960*17 = 16320 >= 16000)

typedef float v4f __attribute__((ext_vector_type(4)));

// ws layout (floats):
//  f[0] = S  f[1] = num_pos  i[2] = last (init -1)  i[3] = corr block counter
//  f[4 .. 4+BK) = l_bk   f[16384 .. 16384+NM) = multiplier table M (init 1.0)
#define OFF_LBK 4
#define OFF_M   16384

__constant__ float c_gammas[15] = {2.7f,2.1f,2.4f,2.0f,3.0f,2.9f,3.0f,2.5f,
                                   2.1f,2.6f,2.0f,2.1f,2.7f,2.4f,2.2f};

// Raw HW transcendentals (glibc collides with __exp2f/__log2f names):
#define EXP2F(x) __builtin_amdgcn_exp2f(x)
#define LOG2F(x) __builtin_amdgcn_logf(x)
#define LN2 0.69314718055994530942f

__device__ __forceinline__ float elem(float p, float g, float gam, float& np) {
    float t    = 1.0f - g;
    float t2   = t * t;
    float negw = (g < 1.0f) ? t2 * t2 : 0.0f;          // (1-g)^4 * neg_ind
    float pw   = EXP2F(gam * LOG2F(p));                // p^gam (0 -> 0)
    float v    = (LN2 * LOG2F(1.0f - p + 1e-12f)) * pw * negw;
    if (g == 1.0f) {                                   // ~never taken
        np += 1.0f;
        v += (LN2 * LOG2F(p + 1e-12f)) * EXP2F(gam * LOG2F(1.0f - p));
    }
    return v;
}

// Sum of 4 elems, UNSCALED by gamma (gamma block-uniform, factored out).
__device__ __forceinline__ float elem4(v4f p, v4f g, float gam, float& np) {
    return elem(p.x, g.x, gam, np) + elem(p.y, g.y, gam, np)
         + elem(p.z, g.z, gam, np) + elem(p.w, g.w, gam, np);
}

__device__ __forceinline__ float blockReduceSum(float v) {
    __shared__ float sh[4];
    #pragma unroll
    for (int o = 32; o > 0; o >>= 1) v += __shfl_down(v, o);
    int lane = threadIdx.x & 63, w = threadIdx.x >> 6;
    if (lane == 0) sh[w] = v;
    __syncthreads();
    float r = 0.0f;
    if (threadIdx.x == 0) r = sh[0] + sh[1] + sh[2] + sh[3];
    __syncthreads();
    return r;   // valid on thread 0 only
}

// ---- init: zero scalars, last=-1, corr counter=0, M=1.0 ----
__global__ __launch_bounds__(256) void k_init(float* ws) {
    int i = blockIdx.x * blockDim.x + threadIdx.x;
    if (i == 0) {
        ws[0] = 0.0f;
        ws[1] = 0.0f;
        ((int*)ws)[2] = -1;
        ((int*)ws)[3] = 0;
    }
    if (i < NM) ws[OFF_M + i] = 1.0f;
}

#define NTL(p) __builtin_nontemporal_load(p)
#define SB __builtin_amdgcn_sched_barrier(0);

#define PREF(P,G,off) \
    P##0 = NTL(pb + (off));       G##0 = NTL(gb + (off)); \
    P##1 = NTL(pb + (off) + 256); G##1 = NTL(gb + (off) + 256); \
    P##2 = NTL(pb + (off) + 512); G##2 = NTL(gb + (off) + 512); \
    P##3 = NTL(pb + (off) + 768); G##3 = NTL(gb + (off) + 768);

#define COMP(P,G) \
    sacc += elem4(P##0, G##0, gam, np); sacc += elem4(P##1, G##1, gam, np); \
    sacc += elem4(P##2, G##2, gam, np); sacc += elem4(P##3, G##3, gam, np);

// ---- fused: distributed per-(b,k) preamble + pipelined slab streaming ----
__global__ __launch_bounds__(256, 4) void k_fused(const v4f*   __restrict__ pred4,
                                                  const v4f*   __restrict__ gt4,
                                                  const float* __restrict__ output,
                                                  const int*   __restrict__ mask,
                                                  const int*   __restrict__ ind,
                                                  const float* __restrict__ target,
                                                  const int*   __restrict__ inde,
                                                  float* ws) {
    const int tid = threadIdx.x;
    const int blk = blockIdx.x;

    // --- per-(b,k) work, 17 items on lanes 0..16 of wave 0 (was k_bk) ---
    int lastv = -1;
    if (tid < BKPB) {
        int t = blk * BKPB + tid;
        if (t < BK) {
            int b = t / KK;
            int pos = ind[t];                                // 0..HW-1
            const float* ob = output + (size_t)b * 2 * HW;
            float p0 = ob[pos];
            float p1 = ob[HW + pos];
            float d0 = p0 - target[t*2 + 0];
            float d1 = p1 - target[t*2 + 1];
            float a0 = fabsf(d0), a1 = fabsf(d1);
            float h0 = (a0 < 1.0f) ? 0.5f*d0*d0 : a0 - 0.5f;
            float h1 = (a1 < 1.0f) ? 0.5f*d1*d1 : a1 - 0.5f;
            float l  = 0.5f * (h0 + h1);
            ws[OFF_LBK + t] = l;
            if (mask[t] != 0) {
                lastv = t;
                float factor = atanf(l) * 0.63661977236758134308f;  // 2/pi
                int ch = inde[t*3 + 0];
                int yy = inde[t*3 + 1];
                int xx = inde[t*3 + 2];
                int mi = ((b*NCLS + ch)*16 + yy)*16 + xx;
                unsigned int* addr = (unsigned int*)(ws + OFF_M + mi);
                unsigned int old = *addr, assumed;
                do {
                    assumed = old;
                    float nv = __uint_as_float(assumed) * factor;
                    old = atomicCAS(addr, assumed, __float_as_uint(nv));
                } while (old != assumed);
            }
        }
    }
    // items live in lanes 0..16 of wave 0; tree-max over 32 lanes
    #pragma unroll
    for (int o = 16; o > 0; o >>= 1) lastv = max(lastv, __shfl_down(lastv, o));
    if (tid == 0 && lastv >= 0) atomicMax(((int*)ws) + 2, lastv);

    // --- pipelined streaming sweep over this block's half slab ---
    const int slab = blk >> 1;               // (b*15 + c)
    const int c    = slab % NCLS;            // SGPR-uniform
    const float gam = c_gammas[c];           // one scalar load per block
    const v4f* pb = pred4 + slab * SLAB4 + (blk & 1) * HALF4 + tid;
    const v4f* gb = gt4   + slab * SLAB4 + (blk & 1) * HALF4 + tid;

    float sacc = 0.0f, np = 0.0f;
    v4f pA0, pA1, pA2, pA3, gA0, gA1, gA2, gA3;
    v4f pB0, pB1, pB2, pB3, gB0, gB1, gB2, gB3;

    PREF(pA, gA, 0)                          // prologue: batch 0 -> A
    PREF(pB, gB, 1024) SB COMP(pA, gA)       // prefetch 1, compute 0
    PREF(pA, gA, 2048) SB COMP(pB, gB)
    PREF(pB, gB, 3072) SB COMP(pA, gA)
    PREF(pA, gA, 4096) SB COMP(pB, gB)
    PREF(pB, gB, 5120) SB COMP(pA, gA)
    PREF(pA, gA, 6144) SB COMP(pB, gB)
    PREF(pB, gB, 7168) SB COMP(pA, gA)
    COMP(pB, gB)                             // epilogue: batch 7

    float acc = gam * sacc;                  // gamma factored out

    float bs = blockReduceSum(acc);
    if (tid == 0 && bs != 0.0f) atomicAdd(&ws[0], bs);
    float bn = blockReduceSum(np);
    if (tid == 0 && bn != 0.0f) atomicAdd(&ws[1], bn);
}

// ---- correction at scatter-modified locations + fused finalize ----
// grid must be exactly NM/256 = 480 blocks (counter pattern assumes it).
__global__ __launch_bounds__(256) void k_corr(const float* __restrict__ pred,
                                              const float* __restrict__ gt,
                                              float* ws, float* out) {
    int i = blockIdx.x * blockDim.x + threadIdx.x;
    float acc = 0.0f, dummy = 0.0f;
    float m = ws[OFF_M + i];
    if (m != 1.0f) {
        int x  = i & 15;
        int y  = (i >> 4) & 15;
        int bc = i >> 8;
        int c  = bc % NCLS;
        size_t off = ((size_t)bc << 16) + (size_t)(y * WW + x);
        float p = pred[off];
        float g = gt[off];
        float gam = c_gammas[c];
        acc = gam * (elem(p * m, g, gam, dummy) - elem(p, g, gam, dummy));
    }
    float bs = blockReduceSum(acc);
    if (threadIdx.x == 0) {
        if (bs != 0.0f) atomicAdd(&ws[0], bs);
        __threadfence();                                   // flush my add
        int done = atomicAdd(((int*)ws) + 3, 1);
        if (done == gridDim.x - 1) {                       // last block finalizes
            float S  = atomicAdd(&ws[0], 0.0f);            // coherent reads
            float np = atomicAdd(&ws[1], 0.0f);
            int last = ((volatile int*)ws)[2];             // written by k_fused (prior kernel)
            float loss0 = (last >= 0) ? ws[OFF_LBK + last] : 0.0f;
            float loss = loss0 - 0.5f * S;
            out[0] = (np == 0.0f) ? loss : loss / np;
        }
    }
}

extern "C" void kernel_launch(void* const* d_in, const int* in_sizes, int n_in,
                              void* d_out, int out_size, void* d_ws, size_t ws_size,
                              hipStream_t stream) {
    const float* pred   = (const float*)d_in[0];
    const float* gt     = (const float*)d_in[1];
    const float* output = (const float*)d_in[2];
    const int*   mask   = (const int*)d_in[3];
    const int*   ind    = (const int*)d_in[4];
    const float* target = (const float*)d_in[5];
    const int*   inde   = (const int*)d_in[6];
    float* ws  = (float*)d_ws;
    float* out = (float*)d_out;

    k_init <<<(NM + 255)/256, 256, 0, stream>>>(ws);
    k_fused<<<FG, FT, 0, stream>>>((const v4f*)pred, (const v4f*)gt,
                                   output, mask, ind, target, inde, ws);
    k_corr <<<NM/256, 256, 0, stream>>>(pred, gt, ws, out);
}

// Round 4
// 295.109 us; speedup vs baseline: 1.1833x; 1.1014x over previous
//
#include <hip/hip_runtime.h>
#include <math.h>

#define BB 32
#define NCLS 15
#define HH 256
#define WW 256
#define KK 500
#define HW (HH*WW)                 // 65536
#define NELEM (BB*NCLS*HW)         // 31457280
#define N4 (NELEM/4)               // 7864320 float4s
#define NM (BB*NCLS*16*16)         // 122880 multiplier slots
#define BK (BB*KK)                 // 16000

// R4: R3 pipeline minus the spill trigger. R3's __launch_bounds__(256,4)
// made the allocator chase the 64-VGPR/8-wave tier and spill the 16 in-
// flight v4f to scratch: WRITE_SIZE 135 MB (vs ~65 KB logical), VGPR=64,
// useful BW only ~2.4 TB/s. Plain __launch_bounds__(256) lifts the cap to
// 512 so the double-buffered register pipeline (~100 VGPR live) stays in
// registers. 960 blocks (half (b,c) slab, 8 batches of 1024 float4);
// at ~100-128 VGPR -> 4-5 waves/SIMD, grid still ~fully co-resident.
#define FG 960
#define FT 256
#define SLAB4 16384                // float4s per (b,c) slab
#define HALF4 8192                 // float4s per block
#define BKPB 17                    // bk items per block (960*17 = 16320 >= 16000)

typedef float v4f __attribute__((ext_vector_type(4)));

// ws layout (floats):
//  f[0] = S  f[1] = num_pos  i[2] = last (init -1)  i[3] = corr block counter
//  f[4 .. 4+BK) = l_bk   f[16384 .. 16384+NM) = multiplier table M (init 1.0)
#define OFF_LBK 4
#define OFF_M   16384

__constant__ float c_gammas[15] = {2.7f,2.1f,2.4f,2.0f,3.0f,2.9f,3.0f,2.5f,
                                   2.1f,2.6f,2.0f,2.1f,2.7f,2.4f,2.2f};

// Raw HW transcendentals (glibc collides with __exp2f/__log2f names):
#define EXP2F(x) __builtin_amdgcn_exp2f(x)
#define LOG2F(x) __builtin_amdgcn_logf(x)
#define LN2 0.69314718055994530942f

__device__ __forceinline__ float elem(float p, float g, float gam, float& np) {
    float t    = 1.0f - g;
    float t2   = t * t;
    float negw = (g < 1.0f) ? t2 * t2 : 0.0f;          // (1-g)^4 * neg_ind
    float pw   = EXP2F(gam * LOG2F(p));                // p^gam (0 -> 0)
    float v    = (LN2 * LOG2F(1.0f - p + 1e-12f)) * pw * negw;
    if (g == 1.0f) {                                   // ~never taken
        np += 1.0f;
        v += (LN2 * LOG2F(p + 1e-12f)) * EXP2F(gam * LOG2F(1.0f - p));
    }
    return v;
}

// Sum of 4 elems, UNSCALED by gamma (gamma block-uniform, factored out).
__device__ __forceinline__ float elem4(v4f p, v4f g, float gam, float& np) {
    return elem(p.x, g.x, gam, np) + elem(p.y, g.y, gam, np)
         + elem(p.z, g.z, gam, np) + elem(p.w, g.w, gam, np);
}

__device__ __forceinline__ float blockReduceSum(float v) {
    __shared__ float sh[4];
    #pragma unroll
    for (int o = 32; o > 0; o >>= 1) v += __shfl_down(v, o);
    int lane = threadIdx.x & 63, w = threadIdx.x >> 6;
    if (lane == 0) sh[w] = v;
    __syncthreads();
    float r = 0.0f;
    if (threadIdx.x == 0) r = sh[0] + sh[1] + sh[2] + sh[3];
    __syncthreads();
    return r;   // valid on thread 0 only
}

// ---- init: zero scalars, last=-1, corr counter=0, M=1.0 ----
__global__ __launch_bounds__(256) void k_init(float* ws) {
    int i = blockIdx.x * blockDim.x + threadIdx.x;
    if (i == 0) {
        ws[0] = 0.0f;
        ws[1] = 0.0f;
        ((int*)ws)[2] = -1;
        ((int*)ws)[3] = 0;
    }
    if (i < NM) ws[OFF_M + i] = 1.0f;
}

#define NTL(p) __builtin_nontemporal_load(p)
#define SB __builtin_amdgcn_sched_barrier(0);

#define PREF(P,G,off) \
    P##0 = NTL(pb + (off));       G##0 = NTL(gb + (off)); \
    P##1 = NTL(pb + (off) + 256); G##1 = NTL(gb + (off) + 256); \
    P##2 = NTL(pb + (off) + 512); G##2 = NTL(gb + (off) + 512); \
    P##3 = NTL(pb + (off) + 768); G##3 = NTL(gb + (off) + 768);

#define COMP(P,G) \
    sacc += elem4(P##0, G##0, gam, np); sacc += elem4(P##1, G##1, gam, np); \
    sacc += elem4(P##2, G##2, gam, np); sacc += elem4(P##3, G##3, gam, np);

// ---- fused: distributed per-(b,k) preamble + pipelined slab streaming ----
__global__ __launch_bounds__(256) void k_fused(const v4f*   __restrict__ pred4,
                                               const v4f*   __restrict__ gt4,
                                               const float* __restrict__ output,
                                               const int*   __restrict__ mask,
                                               const int*   __restrict__ ind,
                                               const float* __restrict__ target,
                                               const int*   __restrict__ inde,
                                               float* ws) {
    const int tid = threadIdx.x;
    const int blk = blockIdx.x;

    // --- per-(b,k) work, 17 items on lanes 0..16 of wave 0 (was k_bk) ---
    int lastv = -1;
    if (tid < BKPB) {
        int t = blk * BKPB + tid;
        if (t < BK) {
            int b = t / KK;
            int pos = ind[t];                                // 0..HW-1
            const float* ob = output + (size_t)b * 2 * HW;
            float p0 = ob[pos];
            float p1 = ob[HW + pos];
            float d0 = p0 - target[t*2 + 0];
            float d1 = p1 - target[t*2 + 1];
            float a0 = fabsf(d0), a1 = fabsf(d1);
            float h0 = (a0 < 1.0f) ? 0.5f*d0*d0 : a0 - 0.5f;
            float h1 = (a1 < 1.0f) ? 0.5f*d1*d1 : a1 - 0.5f;
            float l  = 0.5f * (h0 + h1);
            ws[OFF_LBK + t] = l;
            if (mask[t] != 0) {
                lastv = t;
                float factor = atanf(l) * 0.63661977236758134308f;  // 2/pi
                int ch = inde[t*3 + 0];
                int yy = inde[t*3 + 1];
                int xx = inde[t*3 + 2];
                int mi = ((b*NCLS + ch)*16 + yy)*16 + xx;
                unsigned int* addr = (unsigned int*)(ws + OFF_M + mi);
                unsigned int old = *addr, assumed;
                do {
                    assumed = old;
                    float nv = __uint_as_float(assumed) * factor;
                    old = atomicCAS(addr, assumed, __float_as_uint(nv));
                } while (old != assumed);
            }
        }
    }
    // items live in lanes 0..16 of wave 0; tree-max over 32 lanes
    #pragma unroll
    for (int o = 16; o > 0; o >>= 1) lastv = max(lastv, __shfl_down(lastv, o));
    if (tid == 0 && lastv >= 0) atomicMax(((int*)ws) + 2, lastv);

    // --- pipelined streaming sweep over this block's half slab ---
    const int slab = blk >> 1;               // (b*15 + c)
    const int c    = slab % NCLS;            // SGPR-uniform
    const float gam = c_gammas[c];           // one scalar load per block
    const v4f* pb = pred4 + slab * SLAB4 + (blk & 1) * HALF4 + tid;
    const v4f* gb = gt4   + slab * SLAB4 + (blk & 1) * HALF4 + tid;

    float sacc = 0.0f, np = 0.0f;
    v4f pA0, pA1, pA2, pA3, gA0, gA1, gA2, gA3;
    v4f pB0, pB1, pB2, pB3, gB0, gB1, gB2, gB3;

    PREF(pA, gA, 0)                          // prologue: batch 0 -> A
    PREF(pB, gB, 1024) SB COMP(pA, gA)       // prefetch 1, compute 0
    PREF(pA, gA, 2048) SB COMP(pB, gB)
    PREF(pB, gB, 3072) SB COMP(pA, gA)
    PREF(pA, gA, 4096) SB COMP(pB, gB)
    PREF(pB, gB, 5120) SB COMP(pA, gA)
    PREF(pA, gA, 6144) SB COMP(pB, gB)
    PREF(pB, gB, 7168) SB COMP(pA, gA)
    COMP(pB, gB)                             // epilogue: batch 7

    float acc = gam * sacc;                  // gamma factored out

    float bs = blockReduceSum(acc);
    if (tid == 0 && bs != 0.0f) atomicAdd(&ws[0], bs);
    float bn = blockReduceSum(np);
    if (tid == 0 && bn != 0.0f) atomicAdd(&ws[1], bn);
}

// ---- correction at scatter-modified locations + fused finalize ----
// grid must be exactly NM/256 = 480 blocks (counter pattern assumes it).
__global__ __launch_bounds__(256) void k_corr(const float* __restrict__ pred,
                                              const float* __restrict__ gt,
                                              float* ws, float* out) {
    int i = blockIdx.x * blockDim.x + threadIdx.x;
    float acc = 0.0f, dummy = 0.0f;
    float m = ws[OFF_M + i];
    if (m != 1.0f) {
        int x  = i & 15;
        int y  = (i >> 4) & 15;
        int bc = i >> 8;
        int c  = bc % NCLS;
        size_t off = ((size_t)bc << 16) + (size_t)(y * WW + x);
        float p = pred[off];
        float g = gt[off];
        float gam = c_gammas[c];
        acc = gam * (elem(p * m, g, gam, dummy) - elem(p, g, gam, dummy));
    }
    float bs = blockReduceSum(acc);
    if (threadIdx.x == 0) {
        if (bs != 0.0f) atomicAdd(&ws[0], bs);
        __threadfence();                                   // flush my add
        int done = atomicAdd(((int*)ws) + 3, 1);
        if (done == gridDim.x - 1) {                       // last block finalizes
            float S  = atomicAdd(&ws[0], 0.0f);            // coherent reads
            float np = atomicAdd(&ws[1], 0.0f);
            int last = ((volatile int*)ws)[2];             // written by k_fused (prior kernel)
            float loss0 = (last >= 0) ? ws[OFF_LBK + last] : 0.0f;
            float loss = loss0 - 0.5f * S;
            out[0] = (np == 0.0f) ? loss : loss / np;
        }
    }
}

extern "C" void kernel_launch(void* const* d_in, const int* in_sizes, int n_in,
                              void* d_out, int out_size, void* d_ws, size_t ws_size,
                              hipStream_t stream) {
    const float* pred   = (const float*)d_in[0];
    const float* gt     = (const float*)d_in[1];
    const float* output = (const float*)d_in[2];
    const int*   mask   = (const int*)d_in[3];
    const int*   ind    = (const int*)d_in[4];
    const float* target = (const float*)d_in[5];
    const int*   inde   = (const int*)d_in[6];
    float* ws  = (float*)d_ws;
    float* out = (float*)d_out;

    k_init <<<(NM + 255)/256, 256, 0, stream>>>(ws);
    k_fused<<<FG, FT, 0, stream>>>((const v4f*)pred, (const v4f*)gt,
                                   output, mask, ind, target, inde, ws);
    k_corr <<<NM/256, 256, 0, stream>>>(pred, gt, ws, out);
}